// Round 13
// baseline (132.813 us; speedup 1.0000x reference)
//
#include <hip/hip_runtime.h>

#define IN_C 128
#define OUT_C 256
#define LN_EPS 1e-5f
#define BKN 128          // nodes per bucket
#define BKSH 7
#define NBMAX 512        // supports N <= 65536

typedef __attribute__((ext_vector_type(8))) short bf16x8;
typedef __attribute__((ext_vector_type(4))) float f32x4;

__device__ __forceinline__ unsigned int f2bf(float f) {
    unsigned int u = __float_as_uint(f);
    return (u + 0x7fffu + ((u >> 16) & 1u)) >> 16;   // RNE
}
__device__ __forceinline__ float bf_lo(unsigned int p) { return __uint_as_float(p << 16); }
__device__ __forceinline__ float bf_hi(unsigned int p) { return __uint_as_float(p & 0xffff0000u); }

// ---------- zero bucket histogram ----------
__global__ __launch_bounds__(512) void k_zeroG(int* __restrict__ g) {
    g[threadIdx.x] = 0;
}

// ---------- bucket histogram (col>>7) + weight fragments + x->bf16 convert ----------
// Edge histogram is latency-bound; the streaming convert rides under it for free.
__global__ __launch_bounds__(256) void k_hist(const int* __restrict__ col, int* __restrict__ ghist,
                                              const float* __restrict__ Wg, const float* __restrict__ Wr,
                                              unsigned short* __restrict__ wgf,
                                              unsigned short* __restrict__ wrf,
                                              const float* __restrict__ x,
                                              unsigned short* __restrict__ x_bf,
                                              int E, int ncvt) {
    __shared__ int h[NBMAX];
    int t = threadIdx.x;
    int i = blockIdx.x * 256 + t;
    h[t] = 0; h[t + 256] = 0;
    __syncthreads();
    int base = i * 4;
    if (base + 4 <= E) {
        int4 c = *reinterpret_cast<const int4*>(col + base);
        atomicAdd(&h[c.x >> BKSH], 1);
        atomicAdd(&h[c.y >> BKSH], 1);
        atomicAdd(&h[c.z >> BKSH], 1);
        atomicAdd(&h[c.w >> BKSH], 1);
    } else {
        for (int e = base; e < E; ++e) atomicAdd(&h[col[e] >> BKSH], 1);
    }
    // --- x -> bf16 (unscaled), 32 floats/thread ---
    if (i < ncvt) {
        const float4* xv = reinterpret_cast<const float4*>(x) + (size_t)i * 8;
        uint4* dst = reinterpret_cast<uint4*>(x_bf) + (size_t)i * 4;
#pragma unroll
        for (int j = 0; j < 4; ++j) {
            float4 a = xv[j * 2], b = xv[j * 2 + 1];
            uint4 o;
            o.x = f2bf(a.x) | (f2bf(a.y) << 16);
            o.y = f2bf(a.z) | (f2bf(a.w) << 16);
            o.z = f2bf(b.x) | (f2bf(b.y) << 16);
            o.w = f2bf(b.z) | (f2bf(b.w) << 16);
            dst[j] = o;
        }
    }
    // --- weight fragments (first 8192 threads) ---
    if (i < 8192) {
        int wsel = i >> 12;
        int u = i & 4095;
        int ct = u >> 8, kt = (u >> 6) & 3, l = u & 63;
        int k0 = kt * 32 + (l >> 4) * 8;
        int colw = ct * 16 + (l & 15);
        const float* W = wsel ? Wr : Wg;
        unsigned short* Wf = wsel ? wrf : wgf;
        uint4 o;
        unsigned int s[8];
#pragma unroll
        for (int e = 0; e < 8; ++e) s[e] = f2bf(W[(size_t)(k0 + e) * OUT_C + colw]);
        o.x = s[0] | (s[1] << 16); o.y = s[2] | (s[3] << 16);
        o.z = s[4] | (s[5] << 16); o.w = s[6] | (s[7] << 16);
        reinterpret_cast<uint4*>(Wf)[u] = o;
    }
    __syncthreads();
    if (h[t]) atomicAdd(&ghist[t], h[t]);
    if (h[t + 256]) atomicAdd(&ghist[t + 256], h[t + 256]);
}

// ---------- scan bucket counts -> base + cursor ----------
__global__ __launch_bounds__(512) void k_bscan(const int* __restrict__ ghist, int* __restrict__ basep,
                                               int* __restrict__ cursor, int NB, int E) {
    __shared__ int s[NBMAX];
    int t = threadIdx.x;
    int v = (t < NB) ? ghist[t] : 0;
    s[t] = v;
    __syncthreads();
    for (int off = 1; off < NBMAX; off <<= 1) {
        int add = (t >= off) ? s[t - off] : 0;
        __syncthreads();
        s[t] += add;
        __syncthreads();
    }
    if (t < NB) { int ex = s[t] - v; basep[t] = ex; cursor[t] = ex; }
    if (t == 0) basep[NB] = E;
}

// ---------- scatter edges into bucket regions; 1 global atomic per (block,bucket) ----------
__global__ __launch_bounds__(1024) void k_scatter(const int* __restrict__ row, const int* __restrict__ col,
                                                  int* __restrict__ cursor, unsigned int* __restrict__ ebuf,
                                                  int E) {
    __shared__ int h[NBMAX];
    __shared__ int b2[NBMAX];
    int t = threadIdx.x;
    int i = blockIdx.x * 1024 + t;
    if (t < NBMAX) h[t] = 0;
    __syncthreads();
    int base4 = i * 4;
    int lb[4], ls[4], lc_[4], lr_[4];
    bool full = (base4 + 4 <= E);
    if (full) {
        int4 c = *reinterpret_cast<const int4*>(col + base4);
        int4 r = *reinterpret_cast<const int4*>(row + base4);
        lc_[0] = c.x; lc_[1] = c.y; lc_[2] = c.z; lc_[3] = c.w;
        lr_[0] = r.x; lr_[1] = r.y; lr_[2] = r.z; lr_[3] = r.w;
#pragma unroll
        for (int j = 0; j < 4; ++j) { lb[j] = lc_[j] >> BKSH; ls[j] = atomicAdd(&h[lb[j]], 1); }
    } else {
        for (int j = 0; j < 4; ++j) {
            int e = base4 + j;
            if (e < E) {
                lc_[j] = col[e]; lr_[j] = row[e];
                lb[j] = lc_[j] >> BKSH;
                ls[j] = atomicAdd(&h[lb[j]], 1);
            }
        }
    }
    __syncthreads();
    if (t < NBMAX) { int m = h[t]; b2[t] = m ? atomicAdd(&cursor[t], m) : 0; }
    __syncthreads();
    if (full) {
#pragma unroll
        for (int j = 0; j < 4; ++j)
            ebuf[b2[lb[j]] + ls[j]] = ((unsigned)(lc_[j] & (BKN - 1)) << 16) | (unsigned)lr_[j];
    } else {
        for (int j = 0; j < 4; ++j) {
            int e = base4 + j;
            if (e < E)
                ebuf[b2[lb[j]] + ls[j]] = ((unsigned)(lc_[j] & (BKN - 1)) << 16) | (unsigned)lr_[j];
        }
    }
}

// ---------- per bucket: LDS counting sort -> per-node CSR + dinv + xs convert (from x_bf) ----------
__global__ __launch_bounds__(512) void k_prep2(const unsigned int* __restrict__ ebuf,
                                               const int* __restrict__ basep,
                                               int* __restrict__ ptr,
                                               int* __restrict__ csr_row,
                                               const unsigned short* __restrict__ x_bf,
                                               float* __restrict__ dinv,
                                               unsigned short* __restrict__ xs_bf,
                                               int n, int NB, int E) {
    __shared__ int cnt[BKN];
    __shared__ int sc[BKN];
    __shared__ int cur[BKN];
    int t = threadIdx.x;
    int b = blockIdx.x;
    int c0 = b << BKSH;
    if (t < BKN) cnt[t] = 0;
    __syncthreads();
    int eb = basep[b], ee = basep[b + 1];
    for (int e = eb + t; e < ee; e += 512)
        atomicAdd(&cnt[ebuf[e] >> 16], 1);
    __syncthreads();
    if (t < BKN) sc[t] = cnt[t];
    __syncthreads();
    for (int off = 1; off < BKN; off <<= 1) {
        int add = 0;
        if (t < BKN && t >= off) add = sc[t - off];
        __syncthreads();
        if (t < BKN) sc[t] += add;
        __syncthreads();
    }
    int nloc = n - c0; if (nloc > BKN) nloc = BKN;
    if (t < nloc) {
        int ex = sc[t] - cnt[t];
        cur[t] = ex;
        ptr[c0 + t] = eb + ex;
        dinv[c0 + t] = rsqrtf((float)(cnt[t] + 1));
    }
    if (b == NB - 1 && t == 0) ptr[n] = E;
    __syncthreads();
    for (int e = eb + t; e < ee; e += 512) {
        unsigned r = ebuf[e];
        int s = atomicAdd(&cur[r >> 16], 1);
        csr_row[eb + s] = (int)(r & 0xffffu);
    }
    // xs = dinv * x_bf -> bf16 (reads bf16, halves traffic vs f32 x)
    if (t < nloc * 4) {
        int lr = t >> 2, q = t & 3;
        int rowg = c0 + lr;
        float dn = rsqrtf((float)(cnt[lr] + 1));
        const uint4* xv = reinterpret_cast<const uint4*>(x_bf + (size_t)rowg * IN_C + q * 32);
        uint4* dxs = reinterpret_cast<uint4*>(xs_bf + (size_t)rowg * IN_C + q * 32);
#pragma unroll
        for (int j = 0; j < 4; ++j) {
            uint4 u = xv[j];
            uint4 os;
            os.x = f2bf(bf_lo(u.x) * dn) | (f2bf(bf_hi(u.x) * dn) << 16);
            os.y = f2bf(bf_lo(u.y) * dn) | (f2bf(bf_hi(u.y) * dn) << 16);
            os.z = f2bf(bf_lo(u.z) * dn) | (f2bf(bf_hi(u.z) * dn) << 16);
            os.w = f2bf(bf_lo(u.w) * dn) | (f2bf(bf_hi(u.w) * dn) << 16);
            dxs[j] = os;
        }
    }
}

// ---------- aggregation: agg[c] = dinv[c] * (xs[c] + sum_e xs[r]), unroll x8 ----------
__global__ __launch_bounds__(256) void k_agg(const unsigned int* __restrict__ xs32,
                                             const float* __restrict__ dinv,
                                             const int* __restrict__ ptr,
                                             const int* __restrict__ csr_row,
                                             unsigned short* __restrict__ agg_bf, int n) {
    int c = blockIdx.x * 4 + (threadIdx.x >> 6);
    if (c >= n) return;
    int lane = threadIdx.x & 63;
    float dc = dinv[c];
    unsigned int p = xs32[(size_t)c * 64 + lane];
    float a0 = bf_lo(p), a1 = bf_hi(p);
    int e = ptr[c], end = ptr[c + 1];
    for (; e + 8 <= end; e += 8) {
        int r0 = csr_row[e],     r1 = csr_row[e + 1], r2 = csr_row[e + 2], r3 = csr_row[e + 3];
        int r4 = csr_row[e + 4], r5 = csr_row[e + 5], r6 = csr_row[e + 6], r7 = csr_row[e + 7];
        unsigned int q0 = xs32[(size_t)r0 * 64 + lane];
        unsigned int q1 = xs32[(size_t)r1 * 64 + lane];
        unsigned int q2 = xs32[(size_t)r2 * 64 + lane];
        unsigned int q3 = xs32[(size_t)r3 * 64 + lane];
        unsigned int q4 = xs32[(size_t)r4 * 64 + lane];
        unsigned int q5 = xs32[(size_t)r5 * 64 + lane];
        unsigned int q6 = xs32[(size_t)r6 * 64 + lane];
        unsigned int q7 = xs32[(size_t)r7 * 64 + lane];
        a0 += bf_lo(q0); a1 += bf_hi(q0);
        a0 += bf_lo(q1); a1 += bf_hi(q1);
        a0 += bf_lo(q2); a1 += bf_hi(q2);
        a0 += bf_lo(q3); a1 += bf_hi(q3);
        a0 += bf_lo(q4); a1 += bf_hi(q4);
        a0 += bf_lo(q5); a1 += bf_hi(q5);
        a0 += bf_lo(q6); a1 += bf_hi(q6);
        a0 += bf_lo(q7); a1 += bf_hi(q7);
    }
    for (; e < end; ++e) {
        unsigned int q = xs32[(size_t)csr_row[e] * 64 + lane];
        a0 += bf_lo(q); a1 += bf_hi(q);
    }
    a0 *= dc; a1 *= dc;
    *reinterpret_cast<unsigned int*>(agg_bf + (size_t)c * IN_C + lane * 2) = f2bf(a0) | (f2bf(a1) << 16);
}

// ---------- fused MFMA dual-GEMM (transposed output) + LN + ReLU + residual ----------
__global__ __launch_bounds__(512, 2) void k_mfma(const unsigned short* __restrict__ agg_bf,
                                                 const unsigned short* __restrict__ x_bf,
                                                 const unsigned short* __restrict__ wgf,
                                                 const unsigned short* __restrict__ wrf,
                                                 const float* __restrict__ bgc,
                                                 const float* __restrict__ gamma,
                                                 const float* __restrict__ beta,
                                                 const float* __restrict__ brc,
                                                 float* __restrict__ out, int n, int ntiles, int chunk) {
    int tid = threadIdx.x;
    int w = tid >> 6, l = tid & 63;
    int g = l >> 4, lc = l & 15;

    int t0 = blockIdx.x * chunk;
    int tend = t0 + chunk;
    if (tend > ntiles) tend = ntiles;
    if (t0 >= tend) return;

    bf16x8 Wgf[2][4], Wrf[2][4];
#pragma unroll
    for (int ct2 = 0; ct2 < 2; ++ct2)
#pragma unroll
        for (int kt = 0; kt < 4; ++kt) {
            size_t idx = ((size_t)((w * 2 + ct2) * 4 + kt) * 64 + l) * 8;
            Wgf[ct2][kt] = *reinterpret_cast<const bf16x8*>(wgf + idx);
            Wrf[ct2][kt] = *reinterpret_cast<const bf16x8*>(wrf + idx);
        }

    float4 Pbg[2], Pga[2], Pbe[2], Pbr[2];
#pragma unroll
    for (int ct2 = 0; ct2 < 2; ++ct2) {
        int c0 = (w * 2 + ct2) * 16 + g * 4;
        Pbg[ct2] = *reinterpret_cast<const float4*>(bgc + c0);
        Pga[ct2] = *reinterpret_cast<const float4*>(gamma + c0);
        Pbe[ct2] = *reinterpret_cast<const float4*>(beta + c0);
        Pbr[ct2] = *reinterpret_cast<const float4*>(brc + c0);
    }

    __shared__ float red1[2][8][16], red2[2][8][16];

    bf16x8 Fa[4], Fx[4];
    {
        int mrow = t0 * 16 + lc;
        if (mrow >= n) mrow = n - 1;
        const unsigned short* pa = agg_bf + (size_t)mrow * IN_C + g * 8;
        const unsigned short* px = x_bf   + (size_t)mrow * IN_C + g * 8;
#pragma unroll
        for (int kt = 0; kt < 4; ++kt) {
            Fa[kt] = *reinterpret_cast<const bf16x8*>(pa + kt * 32);
            Fx[kt] = *reinterpret_cast<const bf16x8*>(px + kt * 32);
        }
    }

    for (int t = t0; t < tend; ++t) {
        f32x4 Ag[2], Ar[2];
#pragma unroll
        for (int ct2 = 0; ct2 < 2; ++ct2) {
            Ag[ct2] = (f32x4){0.f, 0.f, 0.f, 0.f};
            Ar[ct2] = (f32x4){0.f, 0.f, 0.f, 0.f};
        }

#pragma unroll
        for (int kt = 0; kt < 4; ++kt)
#pragma unroll
            for (int ct2 = 0; ct2 < 2; ++ct2) {
                Ag[ct2] = __builtin_amdgcn_mfma_f32_16x16x32_bf16(Wgf[ct2][kt], Fa[kt], Ag[ct2], 0, 0, 0);
                Ar[ct2] = __builtin_amdgcn_mfma_f32_16x16x32_bf16(Wrf[ct2][kt], Fx[kt], Ar[ct2], 0, 0, 0);
            }

        {
            int tn = (t + 1 < tend) ? t + 1 : t;
            int mrow = tn * 16 + lc;
            if (mrow >= n) mrow = n - 1;
            const unsigned short* pa = agg_bf + (size_t)mrow * IN_C + g * 8;
            const unsigned short* px = x_bf   + (size_t)mrow * IN_C + g * 8;
#pragma unroll
            for (int kt = 0; kt < 4; ++kt) {
                Fa[kt] = *reinterpret_cast<const bf16x8*>(pa + kt * 32);
                Fx[kt] = *reinterpret_cast<const bf16x8*>(px + kt * 32);
            }
        }

        float s1 = 0.f, s2 = 0.f;
#pragma unroll
        for (int ct2 = 0; ct2 < 2; ++ct2) {
            const float* pb = reinterpret_cast<const float*>(&Pbg[ct2]);
#pragma unroll
            for (int r = 0; r < 4; ++r) {
                float v = Ag[ct2][r] + pb[r];
                Ag[ct2][r] = v;
                s1 += v; s2 += v * v;
            }
        }
        s1 += __shfl_xor(s1, 16); s2 += __shfl_xor(s2, 16);
        s1 += __shfl_xor(s1, 32); s2 += __shfl_xor(s2, 32);

        int buf = t & 1;
        if (l < 16) { red1[buf][w][lc] = s1; red2[buf][w][lc] = s2; }
        __syncthreads();

        float u1 = 0.f, u2 = 0.f;
#pragma unroll
        for (int wv = 0; wv < 8; ++wv) {
            u1 += red1[buf][wv][lc];
            u2 += red2[buf][wv][lc];
        }
        float mu  = u1 * (1.f / OUT_C);
        float var = u2 * (1.f / OUT_C) - mu * mu;
        float rs  = rsqrtf(var + LN_EPS);

        int rown = t * 16 + lc;
        if (rown < n) {
#pragma unroll
            for (int ct2 = 0; ct2 < 2; ++ct2) {
                const float* pg = reinterpret_cast<const float*>(&Pga[ct2]);
                const float* pe = reinterpret_cast<const float*>(&Pbe[ct2]);
                const float* pr = reinterpret_cast<const float*>(&Pbr[ct2]);
                f32x4 o;
#pragma unroll
                for (int r = 0; r < 4; ++r) {
                    float ln = (Ag[ct2][r] - mu) * rs * pg[r] + pe[r];
                    o[r] = fmaxf(ln, 0.f) + Ar[ct2][r] + pr[r];
                }
                *reinterpret_cast<f32x4*>(out + (size_t)rown * OUT_C + (w * 2 + ct2) * 16 + g * 4) = o;
            }
        }
    }
}

extern "C" void kernel_launch(void* const* d_in, const int* in_sizes, int n_in,
                              void* d_out, int out_size, void* d_ws, size_t ws_size,
                              hipStream_t stream) {
    const float* x     = (const float*)d_in[0];
    const int*   ei    = (const int*)d_in[1];
    const float* Wg    = (const float*)d_in[2];
    const float* bg    = (const float*)d_in[3];
    const float* gamma = (const float*)d_in[4];
    const float* beta  = (const float*)d_in[5];
    const float* Wr    = (const float*)d_in[6];
    const float* br    = (const float*)d_in[7];
    float* out = (float*)d_out;

    int N = in_sizes[0] / IN_C;
    int E = in_sizes[1] / 2;
    const int* row = ei;
    const int* col = ei + E;

    char* ws = (char*)d_ws;
    size_t off = 0;
    auto alloc = [&](size_t bytes) -> void* {
        void* p = ws + off;
        off += (bytes + 255) & ~(size_t)255;
        return p;
    };
    unsigned short* x_bf   = (unsigned short*)alloc((size_t)N * IN_C * 2);
    unsigned short* xs_bf  = (unsigned short*)alloc((size_t)N * IN_C * 2);
    unsigned short* agg_bf = (unsigned short*)alloc((size_t)N * IN_C * 2);
    unsigned short* wgf    = (unsigned short*)alloc((size_t)IN_C * OUT_C * 2);
    unsigned short* wrf    = (unsigned short*)alloc((size_t)IN_C * OUT_C * 2);
    float* dinv   = (float*)alloc((size_t)N * sizeof(float));
    int*   ghist  = (int*)alloc(NBMAX * sizeof(int));
    int*   basep  = (int*)alloc((NBMAX + 1) * sizeof(int));
    int*   cursor = (int*)alloc(NBMAX * sizeof(int));
    int*   ptr    = (int*)alloc((size_t)(N + 1) * sizeof(int));
    unsigned int* ebuf = (unsigned int*)alloc((size_t)E * sizeof(unsigned int));
    int*   csr_row = (int*)alloc((size_t)E * sizeof(int));
    (void)ws_size; (void)n_in; (void)out_size;

    int NB = (N + BKN - 1) >> BKSH;                 // 391
    int ncvt = N * (IN_C / 32);                      // 200000 convert threads
    int nbE4 = (E + 1023) / 1024;                    // 782 blocks = 200192 threads >= ncvt
    int ntiles = (N + 15) / 16;
    int ngrid  = 512;
    int chunk  = (ntiles + ngrid - 1) / ngrid;

    k_zeroG  <<<1, 512, 0, stream>>>(ghist);
    k_hist   <<<nbE4, 256, 0, stream>>>(col, ghist, Wg, Wr, wgf, wrf, x, x_bf, E, ncvt);
    k_bscan  <<<1, 512, 0, stream>>>(ghist, basep, cursor, NB, E);
    k_scatter<<<(E + 4095) / 4096, 1024, 0, stream>>>(row, col, cursor, ebuf, E);
    k_prep2  <<<NB, 512, 0, stream>>>(ebuf, basep, ptr, csr_row, x_bf, dinv, xs_bf, N, NB, E);
    k_agg    <<<(N + 3) / 4, 256, 0, stream>>>((const unsigned int*)xs_bf, dinv, ptr, csr_row, agg_bf, N);
    k_mfma   <<<ngrid, 512, 0, stream>>>(agg_bf, x_bf, wgf, wrf, bg, gamma, beta, br,
                                         out, N, ntiles, chunk);
}

// Round 14
// 127.299 us; speedup vs baseline: 1.0433x; 1.0433x over previous
//
#include <hip/hip_runtime.h>

#define IN_C 128
#define OUT_C 256
#define LN_EPS 1e-5f
#define BKN 128          // nodes per bucket
#define BKSH 7
#define NBMAX 512        // supports N <= 65536

typedef __attribute__((ext_vector_type(8))) short bf16x8;
typedef __attribute__((ext_vector_type(4))) float f32x4;

__device__ __forceinline__ unsigned int f2bf(float f) {
    unsigned int u = __float_as_uint(f);
    return (u + 0x7fffu + ((u >> 16) & 1u)) >> 16;   // RNE
}
__device__ __forceinline__ float bf_lo(unsigned int p) { return __uint_as_float(p << 16); }
__device__ __forceinline__ float bf_hi(unsigned int p) { return __uint_as_float(p & 0xffff0000u); }

// ---------- zero bucket histogram ----------
__global__ __launch_bounds__(512) void k_zeroG(int* __restrict__ g) {
    g[threadIdx.x] = 0;
}

// ---------- bucket histogram (col>>7) + weight fragments + x->bf16 convert ----------
__global__ __launch_bounds__(256) void k_hist(const int* __restrict__ col, int* __restrict__ ghist,
                                              const float* __restrict__ Wg, const float* __restrict__ Wr,
                                              unsigned short* __restrict__ wgf,
                                              unsigned short* __restrict__ wrf,
                                              const float* __restrict__ x,
                                              unsigned short* __restrict__ x_bf,
                                              int E, int ncvt) {
    __shared__ int h[NBMAX];
    int t = threadIdx.x;
    int i = blockIdx.x * 256 + t;
    h[t] = 0; h[t + 256] = 0;
    __syncthreads();
    int base = i * 4;
    if (base + 4 <= E) {
        int4 c = *reinterpret_cast<const int4*>(col + base);
        atomicAdd(&h[c.x >> BKSH], 1);
        atomicAdd(&h[c.y >> BKSH], 1);
        atomicAdd(&h[c.z >> BKSH], 1);
        atomicAdd(&h[c.w >> BKSH], 1);
    } else {
        for (int e = base; e < E; ++e) atomicAdd(&h[col[e] >> BKSH], 1);
    }
    if (i < ncvt) {
        const float4* xv = reinterpret_cast<const float4*>(x) + (size_t)i * 8;
        uint4* dst = reinterpret_cast<uint4*>(x_bf) + (size_t)i * 4;
#pragma unroll
        for (int j = 0; j < 4; ++j) {
            float4 a = xv[j * 2], b = xv[j * 2 + 1];
            uint4 o;
            o.x = f2bf(a.x) | (f2bf(a.y) << 16);
            o.y = f2bf(a.z) | (f2bf(a.w) << 16);
            o.z = f2bf(b.x) | (f2bf(b.y) << 16);
            o.w = f2bf(b.z) | (f2bf(b.w) << 16);
            dst[j] = o;
        }
    }
    if (i < 8192) {
        int wsel = i >> 12;
        int u = i & 4095;
        int ct = u >> 8, kt = (u >> 6) & 3, l = u & 63;
        int k0 = kt * 32 + (l >> 4) * 8;
        int colw = ct * 16 + (l & 15);
        const float* W = wsel ? Wr : Wg;
        unsigned short* Wf = wsel ? wrf : wgf;
        uint4 o;
        unsigned int s[8];
#pragma unroll
        for (int e = 0; e < 8; ++e) s[e] = f2bf(W[(size_t)(k0 + e) * OUT_C + colw]);
        o.x = s[0] | (s[1] << 16); o.y = s[2] | (s[3] << 16);
        o.z = s[4] | (s[5] << 16); o.w = s[6] | (s[7] << 16);
        reinterpret_cast<uint4*>(Wf)[u] = o;
    }
    __syncthreads();
    if (h[t]) atomicAdd(&ghist[t], h[t]);
    if (h[t + 256]) atomicAdd(&ghist[t + 256], h[t + 256]);
}

// ---------- scan bucket counts -> base + cursor ----------
__global__ __launch_bounds__(512) void k_bscan(const int* __restrict__ ghist, int* __restrict__ basep,
                                               int* __restrict__ cursor, int NB, int E) {
    __shared__ int s[NBMAX];
    int t = threadIdx.x;
    int v = (t < NB) ? ghist[t] : 0;
    s[t] = v;
    __syncthreads();
    for (int off = 1; off < NBMAX; off <<= 1) {
        int add = (t >= off) ? s[t - off] : 0;
        __syncthreads();
        s[t] += add;
        __syncthreads();
    }
    if (t < NB) { int ex = s[t] - v; basep[t] = ex; cursor[t] = ex; }
    if (t == 0) basep[NB] = E;
}

// ---------- scatter edges into bucket regions; 1 global atomic per (block,bucket) ----------
__global__ __launch_bounds__(1024) void k_scatter(const int* __restrict__ row, const int* __restrict__ col,
                                                  int* __restrict__ cursor, unsigned int* __restrict__ ebuf,
                                                  int E) {
    __shared__ int h[NBMAX];
    __shared__ int b2[NBMAX];
    int t = threadIdx.x;
    int i = blockIdx.x * 1024 + t;
    if (t < NBMAX) h[t] = 0;
    __syncthreads();
    int base4 = i * 4;
    int lb[4], ls[4], lc_[4], lr_[4];
    bool full = (base4 + 4 <= E);
    if (full) {
        int4 c = *reinterpret_cast<const int4*>(col + base4);
        int4 r = *reinterpret_cast<const int4*>(row + base4);
        lc_[0] = c.x; lc_[1] = c.y; lc_[2] = c.z; lc_[3] = c.w;
        lr_[0] = r.x; lr_[1] = r.y; lr_[2] = r.z; lr_[3] = r.w;
#pragma unroll
        for (int j = 0; j < 4; ++j) { lb[j] = lc_[j] >> BKSH; ls[j] = atomicAdd(&h[lb[j]], 1); }
    } else {
        for (int j = 0; j < 4; ++j) {
            int e = base4 + j;
            if (e < E) {
                lc_[j] = col[e]; lr_[j] = row[e];
                lb[j] = lc_[j] >> BKSH;
                ls[j] = atomicAdd(&h[lb[j]], 1);
            }
        }
    }
    __syncthreads();
    if (t < NBMAX) { int m = h[t]; b2[t] = m ? atomicAdd(&cursor[t], m) : 0; }
    __syncthreads();
    if (full) {
#pragma unroll
        for (int j = 0; j < 4; ++j)
            ebuf[b2[lb[j]] + ls[j]] = ((unsigned)(lc_[j] & (BKN - 1)) << 16) | (unsigned)lr_[j];
    } else {
        for (int j = 0; j < 4; ++j) {
            int e = base4 + j;
            if (e < E)
                ebuf[b2[lb[j]] + ls[j]] = ((unsigned)(lc_[j] & (BKN - 1)) << 16) | (unsigned)lr_[j];
        }
    }
}

// ---------- per bucket: LDS counting sort -> per-node CSR + dinv + xs convert (from x_bf) ----------
__global__ __launch_bounds__(512) void k_prep2(const unsigned int* __restrict__ ebuf,
                                               const int* __restrict__ basep,
                                               int* __restrict__ ptr,
                                               int* __restrict__ csr_row,
                                               const unsigned short* __restrict__ x_bf,
                                               float* __restrict__ dinv,
                                               unsigned short* __restrict__ xs_bf,
                                               int n, int NB, int E) {
    __shared__ int cnt[BKN];
    __shared__ int sc[BKN];
    __shared__ int cur[BKN];
    int t = threadIdx.x;
    int b = blockIdx.x;
    int c0 = b << BKSH;
    if (t < BKN) cnt[t] = 0;
    __syncthreads();
    int eb = basep[b], ee = basep[b + 1];
    for (int e = eb + t; e < ee; e += 512)
        atomicAdd(&cnt[ebuf[e] >> 16], 1);
    __syncthreads();
    if (t < BKN) sc[t] = cnt[t];
    __syncthreads();
    for (int off = 1; off < BKN; off <<= 1) {
        int add = 0;
        if (t < BKN && t >= off) add = sc[t - off];
        __syncthreads();
        if (t < BKN) sc[t] += add;
        __syncthreads();
    }
    int nloc = n - c0; if (nloc > BKN) nloc = BKN;
    if (t < nloc) {
        int ex = sc[t] - cnt[t];
        cur[t] = ex;
        ptr[c0 + t] = eb + ex;
        dinv[c0 + t] = rsqrtf((float)(cnt[t] + 1));
    }
    if (b == NB - 1 && t == 0) ptr[n] = E;
    __syncthreads();
    for (int e = eb + t; e < ee; e += 512) {
        unsigned r = ebuf[e];
        int s = atomicAdd(&cur[r >> 16], 1);
        csr_row[eb + s] = (int)(r & 0xffffu);
    }
    if (t < nloc * 4) {
        int lr = t >> 2, q = t & 3;
        int rowg = c0 + lr;
        float dn = rsqrtf((float)(cnt[lr] + 1));
        const uint4* xv = reinterpret_cast<const uint4*>(x_bf + (size_t)rowg * IN_C + q * 32);
        uint4* dxs = reinterpret_cast<uint4*>(xs_bf + (size_t)rowg * IN_C + q * 32);
#pragma unroll
        for (int j = 0; j < 4; ++j) {
            uint4 u = xv[j];
            uint4 os;
            os.x = f2bf(bf_lo(u.x) * dn) | (f2bf(bf_hi(u.x) * dn) << 16);
            os.y = f2bf(bf_lo(u.y) * dn) | (f2bf(bf_hi(u.y) * dn) << 16);
            os.z = f2bf(bf_lo(u.z) * dn) | (f2bf(bf_hi(u.z) * dn) << 16);
            os.w = f2bf(bf_lo(u.w) * dn) | (f2bf(bf_hi(u.w) * dn) << 16);
            dxs[j] = os;
        }
    }
}

// ---------- aggregation: agg[c] = dinv[c] * (xs[c] + sum_e xs[r]), unroll x8 ----------
__global__ __launch_bounds__(256) void k_agg(const unsigned int* __restrict__ xs32,
                                             const float* __restrict__ dinv,
                                             const int* __restrict__ ptr,
                                             const int* __restrict__ csr_row,
                                             unsigned short* __restrict__ agg_bf, int n) {
    int c = blockIdx.x * 4 + (threadIdx.x >> 6);
    if (c >= n) return;
    int lane = threadIdx.x & 63;
    float dc = dinv[c];
    unsigned int p = xs32[(size_t)c * 64 + lane];
    float a0 = bf_lo(p), a1 = bf_hi(p);
    int e = ptr[c], end = ptr[c + 1];
    for (; e + 8 <= end; e += 8) {
        int r0 = csr_row[e],     r1 = csr_row[e + 1], r2 = csr_row[e + 2], r3 = csr_row[e + 3];
        int r4 = csr_row[e + 4], r5 = csr_row[e + 5], r6 = csr_row[e + 6], r7 = csr_row[e + 7];
        unsigned int q0 = xs32[(size_t)r0 * 64 + lane];
        unsigned int q1 = xs32[(size_t)r1 * 64 + lane];
        unsigned int q2 = xs32[(size_t)r2 * 64 + lane];
        unsigned int q3 = xs32[(size_t)r3 * 64 + lane];
        unsigned int q4 = xs32[(size_t)r4 * 64 + lane];
        unsigned int q5 = xs32[(size_t)r5 * 64 + lane];
        unsigned int q6 = xs32[(size_t)r6 * 64 + lane];
        unsigned int q7 = xs32[(size_t)r7 * 64 + lane];
        a0 += bf_lo(q0); a1 += bf_hi(q0);
        a0 += bf_lo(q1); a1 += bf_hi(q1);
        a0 += bf_lo(q2); a1 += bf_hi(q2);
        a0 += bf_lo(q3); a1 += bf_hi(q3);
        a0 += bf_lo(q4); a1 += bf_hi(q4);
        a0 += bf_lo(q5); a1 += bf_hi(q5);
        a0 += bf_lo(q6); a1 += bf_hi(q6);
        a0 += bf_lo(q7); a1 += bf_hi(q7);
    }
    for (; e < end; ++e) {
        unsigned int q = xs32[(size_t)csr_row[e] * 64 + lane];
        a0 += bf_lo(q); a1 += bf_hi(q);
    }
    a0 *= dc; a1 *= dc;
    *reinterpret_cast<unsigned int*>(agg_bf + (size_t)c * IN_C + lane * 2) = f2bf(a0) | (f2bf(a1) << 16);
}

// ---------- fused MFMA dual-GEMM (transposed output) + LN + ReLU + residual ----------
// LDS-staged output: epilogue writes go to a padded LDS tile; block then copies the
// 16KB tile to global with perfectly coalesced dwordx4 stores (64 lanes x 16B contiguous).
__global__ __launch_bounds__(512, 2) void k_mfma(const unsigned short* __restrict__ agg_bf,
                                                 const unsigned short* __restrict__ x_bf,
                                                 const unsigned short* __restrict__ wgf,
                                                 const unsigned short* __restrict__ wrf,
                                                 const float* __restrict__ bgc,
                                                 const float* __restrict__ gamma,
                                                 const float* __restrict__ beta,
                                                 const float* __restrict__ brc,
                                                 float* __restrict__ out, int n, int ntiles, int chunk) {
    int tid = threadIdx.x;
    int w = tid >> 6, l = tid & 63;
    int g = l >> 4, lc = l & 15;

    int t0 = blockIdx.x * chunk;
    int tend = t0 + chunk;
    if (tend > ntiles) tend = ntiles;
    if (t0 >= tend) return;

    bf16x8 Wgf[2][4], Wrf[2][4];
#pragma unroll
    for (int ct2 = 0; ct2 < 2; ++ct2)
#pragma unroll
        for (int kt = 0; kt < 4; ++kt) {
            size_t idx = ((size_t)((w * 2 + ct2) * 4 + kt) * 64 + l) * 8;
            Wgf[ct2][kt] = *reinterpret_cast<const bf16x8*>(wgf + idx);
            Wrf[ct2][kt] = *reinterpret_cast<const bf16x8*>(wrf + idx);
        }

    float4 Pbg[2], Pga[2], Pbe[2], Pbr[2];
#pragma unroll
    for (int ct2 = 0; ct2 < 2; ++ct2) {
        int c0 = (w * 2 + ct2) * 16 + g * 4;
        Pbg[ct2] = *reinterpret_cast<const float4*>(bgc + c0);
        Pga[ct2] = *reinterpret_cast<const float4*>(gamma + c0);
        Pbe[ct2] = *reinterpret_cast<const float4*>(beta + c0);
        Pbr[ct2] = *reinterpret_cast<const float4*>(brc + c0);
    }

    __shared__ float red1[2][8][16], red2[2][8][16];
    __shared__ float otile[16][OUT_C + 4];   // pad breaks 1KB-stride bank conflicts

    bf16x8 Fa[4], Fx[4];
    {
        int mrow = t0 * 16 + lc;
        if (mrow >= n) mrow = n - 1;
        const unsigned short* pa = agg_bf + (size_t)mrow * IN_C + g * 8;
        const unsigned short* px = x_bf   + (size_t)mrow * IN_C + g * 8;
#pragma unroll
        for (int kt = 0; kt < 4; ++kt) {
            Fa[kt] = *reinterpret_cast<const bf16x8*>(pa + kt * 32);
            Fx[kt] = *reinterpret_cast<const bf16x8*>(px + kt * 32);
        }
    }

    for (int t = t0; t < tend; ++t) {
        f32x4 Ag[2], Ar[2];
#pragma unroll
        for (int ct2 = 0; ct2 < 2; ++ct2) {
            Ag[ct2] = (f32x4){0.f, 0.f, 0.f, 0.f};
            Ar[ct2] = (f32x4){0.f, 0.f, 0.f, 0.f};
        }

#pragma unroll
        for (int kt = 0; kt < 4; ++kt)
#pragma unroll
            for (int ct2 = 0; ct2 < 2; ++ct2) {
                Ag[ct2] = __builtin_amdgcn_mfma_f32_16x16x32_bf16(Wgf[ct2][kt], Fa[kt], Ag[ct2], 0, 0, 0);
                Ar[ct2] = __builtin_amdgcn_mfma_f32_16x16x32_bf16(Wrf[ct2][kt], Fx[kt], Ar[ct2], 0, 0, 0);
            }

        {
            int tn = (t + 1 < tend) ? t + 1 : t;
            int mrow = tn * 16 + lc;
            if (mrow >= n) mrow = n - 1;
            const unsigned short* pa = agg_bf + (size_t)mrow * IN_C + g * 8;
            const unsigned short* px = x_bf   + (size_t)mrow * IN_C + g * 8;
#pragma unroll
            for (int kt = 0; kt < 4; ++kt) {
                Fa[kt] = *reinterpret_cast<const bf16x8*>(pa + kt * 32);
                Fx[kt] = *reinterpret_cast<const bf16x8*>(px + kt * 32);
            }
        }

        float s1 = 0.f, s2 = 0.f;
#pragma unroll
        for (int ct2 = 0; ct2 < 2; ++ct2) {
            const float* pb = reinterpret_cast<const float*>(&Pbg[ct2]);
#pragma unroll
            for (int r = 0; r < 4; ++r) {
                float v = Ag[ct2][r] + pb[r];
                Ag[ct2][r] = v;
                s1 += v; s2 += v * v;
            }
        }
        s1 += __shfl_xor(s1, 16); s2 += __shfl_xor(s2, 16);
        s1 += __shfl_xor(s1, 32); s2 += __shfl_xor(s2, 32);

        int buf = t & 1;
        if (l < 16) { red1[buf][w][lc] = s1; red2[buf][w][lc] = s2; }
        __syncthreads();   // also orders prior copy-out vs this tile's otile writes

        float u1 = 0.f, u2 = 0.f;
#pragma unroll
        for (int wv = 0; wv < 8; ++wv) {
            u1 += red1[buf][wv][lc];
            u2 += red2[buf][wv][lc];
        }
        float mu  = u1 * (1.f / OUT_C);
        float var = u2 * (1.f / OUT_C) - mu * mu;
        float rs  = rsqrtf(var + LN_EPS);

        // ---- epilogue into LDS tile ----
#pragma unroll
        for (int ct2 = 0; ct2 < 2; ++ct2) {
            const float* pg = reinterpret_cast<const float*>(&Pga[ct2]);
            const float* pe = reinterpret_cast<const float*>(&Pbe[ct2]);
            const float* pr = reinterpret_cast<const float*>(&Pbr[ct2]);
            f32x4 o;
#pragma unroll
            for (int r = 0; r < 4; ++r) {
                float ln = (Ag[ct2][r] - mu) * rs * pg[r] + pe[r];
                o[r] = fmaxf(ln, 0.f) + Ar[ct2][r] + pr[r];
            }
            *reinterpret_cast<f32x4*>(&otile[lc][(w * 2 + ct2) * 16 + g * 4]) = o;
        }
        __syncthreads();

        // ---- coalesced copy-out: 1024 f32x4 pieces, 512 threads x 2 ----
        int rowbase = t * 16;
#pragma unroll
        for (int q = 0; q < 2; ++q) {
            int idx = q * 512 + tid;
            int rr = idx >> 6;
            int cc = (idx & 63) * 4;
            if (rowbase + rr < n) {
                f32x4 v = *reinterpret_cast<const f32x4*>(&otile[rr][cc]);
                *reinterpret_cast<f32x4*>(out + (size_t)(rowbase + rr) * OUT_C + cc) = v;
            }
        }
    }
}

extern "C" void kernel_launch(void* const* d_in, const int* in_sizes, int n_in,
                              void* d_out, int out_size, void* d_ws, size_t ws_size,
                              hipStream_t stream) {
    const float* x     = (const float*)d_in[0];
    const int*   ei    = (const int*)d_in[1];
    const float* Wg    = (const float*)d_in[2];
    const float* bg    = (const float*)d_in[3];
    const float* gamma = (const float*)d_in[4];
    const float* beta  = (const float*)d_in[5];
    const float* Wr    = (const float*)d_in[6];
    const float* br    = (const float*)d_in[7];
    float* out = (float*)d_out;

    int N = in_sizes[0] / IN_C;
    int E = in_sizes[1] / 2;
    const int* row = ei;
    const int* col = ei + E;

    char* ws = (char*)d_ws;
    size_t off = 0;
    auto alloc = [&](size_t bytes) -> void* {
        void* p = ws + off;
        off += (bytes + 255) & ~(size_t)255;
        return p;
    };
    unsigned short* x_bf   = (unsigned short*)alloc((size_t)N * IN_C * 2);
    unsigned short* xs_bf  = (unsigned short*)alloc((size_t)N * IN_C * 2);
    unsigned short* agg_bf = (unsigned short*)alloc((size_t)N * IN_C * 2);
    unsigned short* wgf    = (unsigned short*)alloc((size_t)IN_C * OUT_C * 2);
    unsigned short* wrf    = (unsigned short*)alloc((size_t)IN_C * OUT_C * 2);
    float* dinv   = (float*)alloc((size_t)N * sizeof(float));
    int*   ghist  = (int*)alloc(NBMAX * sizeof(int));
    int*   basep  = (int*)alloc((NBMAX + 1) * sizeof(int));
    int*   cursor = (int*)alloc(NBMAX * sizeof(int));
    int*   ptr    = (int*)alloc((size_t)(N + 1) * sizeof(int));
    unsigned int* ebuf = (unsigned int*)alloc((size_t)E * sizeof(unsigned int));
    int*   csr_row = (int*)alloc((size_t)E * sizeof(int));
    (void)ws_size; (void)n_in; (void)out_size;

    int NB = (N + BKN - 1) >> BKSH;                 // 391
    int ncvt = N * (IN_C / 32);                      // 200000 convert threads
    int nbE4 = (E + 1023) / 1024;                    // 782 blocks = 200192 threads >= ncvt
    int ntiles = (N + 15) / 16;
    int ngrid  = 256;
    int chunk  = (ntiles + ngrid - 1) / ngrid;

    k_zeroG  <<<1, 512, 0, stream>>>(ghist);
    k_hist   <<<nbE4, 256, 0, stream>>>(col, ghist, Wg, Wr, wgf, wrf, x, x_bf, E, ncvt);
    k_bscan  <<<1, 512, 0, stream>>>(ghist, basep, cursor, NB, E);
    k_scatter<<<(E + 4095) / 4096, 1024, 0, stream>>>(row, col, cursor, ebuf, E);
    k_prep2  <<<NB, 512, 0, stream>>>(ebuf, basep, ptr, csr_row, x_bf, dinv, xs_bf, N, NB, E);
    k_agg    <<<(N + 3) / 4, 256, 0, stream>>>((const unsigned int*)xs_bf, dinv, ptr, csr_row, agg_bf, N);
    k_mfma   <<<ngrid, 512, 0, stream>>>(agg_bf, x_bf, wgf, wrf, bg, gamma, beta, br,
                                         out, N, ntiles, chunk);
}